// Round 5
// baseline (261.915 us; speedup 1.0000x reference)
//
#include <hip/hip_runtime.h>

typedef __attribute__((ext_vector_type(4))) int int4v;
typedef __attribute__((ext_vector_type(16))) int int16v;

#define NPIX 100352      // 32*56*56
#define PPIX 107648      // 32*58*58 zero-padded pixels
#define KTAP 2304        // 9*256
#define CHB (PPIX * 16)  // bytes per 16-channel chunk plane: 1,722,368
#define LDB 272          // 256 + 16 pad (16B aligned, 0 bank conflicts measured)
#define BTILE (64 * LDB) // 17,408 B single B buffer

// ---------- kernel 1: weight sign transpose ----------
__global__ __launch_bounds__(256) void quant_w_kernel(const float* __restrict__ Wm,
                                                      signed char* __restrict__ Bt,
                                                      float* __restrict__ Esum) {
  __shared__ signed char sT[64][80];
  __shared__ float red[4];
  const int k0 = blockIdx.x * 64;
  const int c0 = blockIdx.y * 64;
  const int t = threadIdx.x;
  const int cc = t & 63;
  const int r0 = (t >> 6) * 16;
  float s = 0.f;
#pragma unroll
  for (int i = 0; i < 16; ++i) {
    const int k = r0 + i;
    float w = Wm[(long)(k0 + k) * 256 + c0 + cc];
    s += fabsf(w);
    sT[cc][k] = (signed char)((w > 0.f) ? 1 : ((w < 0.f) ? -1 : 0));
  }
#pragma unroll
  for (int o = 32; o > 0; o >>= 1) s += __shfl_down(s, o, 64);
  if ((t & 63) == 0) red[t >> 6] = s;
  __syncthreads();
  if (t == 0) atomicAdd(Esum, red[0] + red[1] + red[2] + red[3]);
  const int co = t >> 2;
  const int kc = (t & 3) * 16;
  int4v v = *(const int4v*)&sT[co][kc];
  *(int4v*)(Bt + (long)(c0 + co) * KTAP + k0 + kc) = v;
}

// ---------- kernel 2: quantize fp32 -> int8 {0..7}, chunk-major padded planes ----------
__global__ __launch_bounds__(256) void quant_x_kernel(const float* __restrict__ x,
                                                      signed char* __restrict__ xqT) {
  const int tid = blockIdx.x * 256 + threadIdx.x;   // 6,422,528 threads
  float4 v = ((const float4*)x)[tid];
  unsigned q;
  q  = (unsigned)(int)rintf(fminf(1.f, fabsf(v.x)) * 7.f);
  q |= ((unsigned)(int)rintf(fminf(1.f, fabsf(v.y)) * 7.f)) << 8;
  q |= ((unsigned)(int)rintf(fminf(1.f, fabsf(v.z)) * 7.f)) << 16;
  q |= ((unsigned)(int)rintf(fminf(1.f, fabsf(v.w)) * 7.f)) << 24;
  const int pix = tid >> 6;
  const int l = tid & 63;
  const int n = pix / 3136;
  const int rem = pix - n * 3136;
  const int h = rem / 56, w = rem - (rem / 56) * 56;
  const int pp = (n * 58 + h + 1) * 58 + (w + 1);
  const int c = l >> 2, j = l & 3;
  *(unsigned*)(xqT + (long)c * CHB + pp * 16 + j * 4) = q;
}

// ---------- kernel 3: implicit-GEMM conv ----------
// BM=128 BN=64 BK=256 (one tap/stage, 9 stages). Wave tile 64x32 -> acc=32 AGPR.
// ~114 combined regs -> 4 waves/SIMD (16 waves/CU). A direct-from-global with
// DEPTH-3 register prefetch; B frag ds_reads DEPTH-2; B staged single-buffer LDS,
// two raw barriers/stage, global loads never drained.
__global__ __launch_bounds__(256, 4) void conv_kernel(const signed char* __restrict__ xqT,
                                                      const signed char* __restrict__ Bt,
                                                      const float* __restrict__ bias,
                                                      const float* __restrict__ Esum,
                                                      float* __restrict__ out) {
  __shared__ signed char Bs[BTILE];

  const int t = threadIdx.x;
  const int lane = t & 63;
  const int wid = t >> 6;
  // bijective XCD swizzle: 3136 = 8 * 392; consecutive swizzled ids = 4 N-tiles of
  // one M-tile (A reuse within an XCD's L2)
  const int bid = blockIdx.x;
  const int tile = (bid & 7) * 392 + (bid >> 3);
  const int m0 = (tile >> 2) * 128;
  const int n0 = (tile & 3) * 64;
  const int wm = (wid & 1) * 64;
  const int wn = (wid >> 1) * 32;
  const int lrow = lane & 31;
  const int half = lane >> 5;          // 16B K-half within a 32-K mfma block

  // padded-pixel base pointers for this lane's two A rows (plane "half" folded in)
  const signed char *ap0, *ap1;
  {
    const int p0 = m0 + wm + lrow;
    const int n_ = p0 / 3136, r_ = p0 - n_ * 3136;
    const int h_ = r_ / 56, w_ = r_ - h_ * 56;
    ap0 = xqT + (long)half * CHB + ((n_ * 58 + h_ + 1) * 58 + (w_ + 1)) * 16;
    const int p1 = p0 + 32;
    const int n2 = p1 / 3136, r2 = p1 - n2 * 3136;
    const int h2 = r2 / 56, w2 = r2 - h2 * 56;
    ap1 = xqT + (long)half * CHB + ((n2 * 58 + h2 + 1) * 58 + (w2 + 1)) * 16;
  }
  auto dp16 = [](int tap) { return ((tap / 3 - 1) * 58 + (tap % 3) - 1) * 16; };

  // B staging: 16 lanes per 256B row chunk, rows (t>>4)+16i, i<4
  const int brow = t >> 4;
  const int bcol = (t & 15) * 16;
  const int gbB = (n0 + brow) * KTAP + bcol;
  const int lbw = brow * LDB + bcol;
  const signed char* brd = Bs + (wn + lrow) * LDB + half * 16;  // B frag read base

  int16v acc0, acc1;
#pragma unroll
  for (int r = 0; r < 16; ++r) { acc0[r] = 0; acc1[r] = 0; }

  // ---- prologue: B(0) in flight; A frags for (s=0, ks=0..2) in flight ----
  int4v rb[4];
#pragma unroll
  for (int i = 0; i < 4; ++i) rb[i] = *(const int4v*)(Bt + gbB + i * (16 * KTAP));
  int4v ra0[4], ra1[4], bf[3];
  {
    const signed char* p0 = ap0 + dp16(0);
    const signed char* p1 = ap1 + dp16(0);
#pragma unroll
    for (int j = 0; j < 3; ++j) {
      ra0[j] = *(const int4v*)(p0 + j * (2 * CHB));
      ra1[j] = *(const int4v*)(p1 + j * (2 * CHB));
    }
  }

#define ITER(ks)                                                                  \
  {                                                                               \
    /* depth-3 A prefetch: frag(ks+3), crossing into next stage when needed */    \
    const signed char* pa0 =                                                      \
        ((ks) + 3 < 8) ? (a0s + ((ks) + 3) * (2 * CHB)) : (a0n + ((ks) - 5) * (2 * CHB)); \
    const signed char* pa1 =                                                      \
        ((ks) + 3 < 8) ? (a1s + ((ks) + 3) * (2 * CHB)) : (a1n + ((ks) - 5) * (2 * CHB)); \
    ra0[((ks) + 3) & 3] = *(const int4v*)pa0;                                     \
    ra1[((ks) + 3) & 3] = *(const int4v*)pa1;                                     \
    /* depth-2 B frag read (same LDS stage buffer only) */                        \
    if ((ks) + 2 < 8) bf[((ks) + 2) % 3] = *(const int4v*)(brd + ((ks) + 2) * 32); \
    __builtin_amdgcn_s_setprio(1);                                                \
    acc0 = __builtin_amdgcn_mfma_i32_32x32x32_i8(ra0[(ks) & 3], bf[(ks) % 3], acc0, 0, 0, 0); \
    acc1 = __builtin_amdgcn_mfma_i32_32x32x32_i8(ra1[(ks) & 3], bf[(ks) % 3], acc1, 0, 0, 0); \
    __builtin_amdgcn_s_setprio(0);                                                \
  }

  for (int s = 0; s < 9; ++s) {
    if (s) __builtin_amdgcn_s_barrier();     // all waves done reading Bs
    // write B(s); compiler inserts counted vmcnt for rb only (issued a stage ago)
#pragma unroll
    for (int i = 0; i < 4; ++i) *(int4v*)(Bs + lbw + i * (16 * LDB)) = rb[i];
    asm volatile("s_waitcnt lgkmcnt(0)" ::: "memory");
    __builtin_amdgcn_sched_barrier(0);
    __builtin_amdgcn_s_barrier();
    __builtin_amdgcn_sched_barrier(0);

    // issue B(s+1) global loads; in flight across the whole compute phase
    if (s < 8) {
      const int go = (s + 1) * 256;
#pragma unroll
      for (int i = 0; i < 4; ++i)
        rb[i] = *(const int4v*)(Bt + gbB + go + i * (16 * KTAP));
    }

    const signed char* a0s = ap0 + dp16(s);
    const signed char* a1s = ap1 + dp16(s);
    const signed char* a0n = ap0 + dp16(s < 8 ? s + 1 : 8);   // clamp: in-bounds, discarded
    const signed char* a1n = ap1 + dp16(s < 8 ? s + 1 : 8);

    // refill B frag pipeline for this stage (exposed once per stage)
    bf[0] = *(const int4v*)(brd);
    bf[1] = *(const int4v*)(brd + 32);

    ITER(0) ITER(1) ITER(2) ITER(3) ITER(4) ITER(5) ITER(6) ITER(7)
  }
#undef ITER

  // epilogue: out = acc * (E/7) + bias
  const float scale = Esum[0] * (1.0f / (589824.0f * 7.0f));
  const int col = n0 + wn + lrow;
  const float bv = bias[col];
#pragma unroll
  for (int r = 0; r < 16; ++r) {
    const int row = (r & 3) + 8 * (r >> 2) + 4 * half;
    out[(long)(m0 + wm + row) * 256 + col] = (float)acc0[r] * scale + bv;
  }
#pragma unroll
  for (int r = 0; r < 16; ++r) {
    const int row = (r & 3) + 8 * (r >> 2) + 4 * half;
    out[(long)(m0 + wm + 32 + row) * 256 + col] = (float)acc1[r] * scale + bv;
  }
}

extern "C" void kernel_launch(void* const* d_in, const int* in_sizes, int n_in,
                              void* d_out, int out_size, void* d_ws, size_t ws_size,
                              hipStream_t stream) {
  const float* x    = (const float*)d_in[0];
  const float* Wm   = (const float*)d_in[1];
  const float* bias = (const float*)d_in[2];
  float* out = (float*)d_out;

  float* Esum = (float*)d_ws;
  signed char* Bt  = (signed char*)d_ws + 256;                // 589,824 B
  signed char* xqT = (signed char*)d_ws + 256 + 589824;       // 27,557,888 B (16 planes)

  hipMemsetAsync(d_ws, 0, 4, stream);
  hipMemsetAsync(xqT, 0, 27557888, stream);                   // zero halo (and planes)
  quant_w_kernel<<<dim3(36, 4), 256, 0, stream>>>(Wm, Bt, Esum);
  quant_x_kernel<<<25088, 256, 0, stream>>>(x, xqT);
  conv_kernel<<<3136, 256, 0, stream>>>(xqT, Bt, bias, Esum, out);
}